// Round 10
// baseline (96.961 us; speedup 1.0000x reference)
//
#include <hip/hip_runtime.h>
#include <math.h>

#define NB 8
#define TT 2048
#define DD 1024
#define NT64 32           // 2048 / 64 tiles
#define NP64 528          // NT64*(NT64+1)/2 lower-tri pairs

typedef __attribute__((ext_vector_type(4))) float floatx4;

__device__ inline float fast_gelu(float x) {
    // tanh(z) = 1 - 2/(exp(2z)+1); __expf -> v_exp_f32
    float z = 0.7978845608028654f * (x + 0.044715f * x * x * x);
    float e = __expf(2.0f * z);
    float th = 1.0f - 2.0f / (e + 1.0f);
    return 0.5f * x * (1.0f + th);
}

// ------- kernel A: gelu + row norm + ema dot -> fp8 out_norm, ema_sim --------
// wave-per-row; ema normalization fused (L2-hot 4KB re-read per wave).
__global__ __launch_bounds__(256) void k_gelu_norm(
        const float* __restrict__ x, const float* __restrict__ ema,
        unsigned int* __restrict__ onrm8, float* __restrict__ ema_sim) {
    int row = blockIdx.x * 4 + (threadIdx.x >> 6);
    int lane = threadIdx.x & 63;
    const float4* xr = reinterpret_cast<const float4*>(x + (size_t)row * DD);
    const float4* er = reinterpret_cast<const float4*>(ema);
    float g[16];
    float ss = 0.f, dt = 0.f, e2 = 0.f;
#pragma unroll
    for (int j = 0; j < 4; ++j) {
        float4 v = xr[j * 64 + lane];
        float4 e = er[j * 64 + lane];
        float vv[4] = {v.x, v.y, v.z, v.w};
        float ee[4] = {e.x, e.y, e.z, e.w};
        e2 += ee[0] * ee[0] + ee[1] * ee[1] + ee[2] * ee[2] + ee[3] * ee[3];
#pragma unroll
        for (int i = 0; i < 4; ++i) {
            float o = fast_gelu(vv[i]);
            g[j * 4 + i] = o;
            ss += o * o;
            dt += o * ee[i];
        }
    }
#pragma unroll
    for (int m = 1; m < 64; m <<= 1) {
        ss += __shfl_xor(ss, m);
        dt += __shfl_xor(dt, m);
        e2 += __shfl_xor(e2, m);
    }
    float inv = 1.0f / fmaxf(sqrtf(ss), 1e-12f);
    float einv = 1.0f / fmaxf(sqrtf(e2), 1e-12f);
    unsigned int* o8 = onrm8 + (size_t)row * (DD / 4);
#pragma unroll
    for (int j = 0; j < 4; ++j) {
        int pk = 0;
        pk = __builtin_amdgcn_cvt_pk_fp8_f32(g[j * 4 + 0] * inv, g[j * 4 + 1] * inv, pk, false);
        pk = __builtin_amdgcn_cvt_pk_fp8_f32(g[j * 4 + 2] * inv, g[j * 4 + 3] * inv, pk, true);
        o8[j * 64 + lane] = (unsigned int)pk;
    }
    if (lane == 0) ema_sim[row] = dt * inv * einv;
}

// -------- kernel B: causal max similarity, barrier-free wave-private GEMM ----
// grid = NB*528 lower-tri 64x64 tile pairs, 64 threads (ONE wave) per block,
// XCD-swizzled (batch per XCD; 2 MB fp8 slice L2-resident). The wave owns the
// whole 64x64 output (4x4 frags of mfma_f32_16x16x32_fp8_fp8), stages its own
// 16 KB A+B K-slab (BK=128 fp8) into double-buffered 32 KB LDS via
// global_load_lds w=16 (XOR-pre-swizzled source), and pipelines with counted
// s_waitcnt vmcnt(16) -- NO __syncthreads anywhere. Overwrite safety: the
// compiler's lgkm waits before each MFMA (data dep on ds_read) precede the
// next stage() in program order, so buf reads complete before restage.
__global__ __launch_bounds__(64) void k_seqmax(const unsigned char* __restrict__ onrm8,
                                               float* __restrict__ part) {
    __shared__ __align__(16) unsigned char lds[2][16384];  // per buf: A@0, B@8192

    int id = blockIdx.x;
    int nid = (id & 7) * NP64 + (id >> 3);       // bijective: 4224 % 8 == 0
    int b = nid / NP64;
    int p = nid % NP64;
    int ti = (int)((sqrtf(8.0f * (float)p + 1.0f) - 1.0f) * 0.5f);
    while ((ti + 1) * (ti + 2) / 2 <= p) ++ti;
    while (ti * (ti + 1) / 2 > p) --ti;
    int sj = p - ti * (ti + 1) / 2;

    int lane = threadIdx.x;
    int rl = lane & 15, g = lane >> 4;

    const unsigned char* Abase = onrm8 + (size_t)(b * TT + ti * 64) * DD;
    const unsigned char* Bbase = onrm8 + (size_t)(b * TT + sj * 64) * DD;

    floatx4 acc[4][4];
#pragma unroll
    for (int i = 0; i < 4; i++)
#pragma unroll
        for (int j = 0; j < 4; j++) acc[i][j] = (floatx4){0.f, 0.f, 0.f, 0.f};

    // stage one 64x128B K-slab pair (8 KB each): 8 chunks of 1 KB per matrix,
    // 16 global_load_lds per lane. LDS dest linear (base + lane*16); global
    // source column XOR-pre-swizzled.
    auto stage = [&](int buf, int kt) {
#pragma unroll
        for (int i = 0; i < 8; ++i) {
            int off = i * 1024 + lane * 16;      // linear LDS byte offset
            int row = off >> 7;                  // 128 B per row
            int colb = (off & 127) ^ ((row & 7) << 4);
            const unsigned char* srcA = Abase + (size_t)row * DD + kt * 128 + colb;
            const unsigned char* srcB = Bbase + (size_t)row * DD + kt * 128 + colb;
            __builtin_amdgcn_global_load_lds(
                (const __attribute__((address_space(1))) unsigned int*)srcA,
                (__attribute__((address_space(3))) unsigned int*)(&lds[buf][0] + i * 1024),
                16, 0, 0);
            __builtin_amdgcn_global_load_lds(
                (const __attribute__((address_space(1))) unsigned int*)srcB,
                (__attribute__((address_space(3))) unsigned int*)(&lds[buf][8192] + i * 1024),
                16, 0, 0);
        }
    };

    stage(0, 0);
    for (int kt = 0; kt < 8; ++kt) {
        int buf = kt & 1;
        if (kt + 1 < 8) {
            stage(buf ^ 1, kt + 1);
            // wait for stage(kt)'s 16 loads; the 16 just issued stay in flight
            asm volatile("s_waitcnt vmcnt(16)" ::: "memory");
        } else {
            asm volatile("s_waitcnt vmcnt(0)" ::: "memory");
        }
        __builtin_amdgcn_sched_barrier(0);
        const unsigned char* Ab = &lds[buf][0];
        const unsigned char* Bb = &lds[buf][8192];
#pragma unroll
        for (int ks = 0; ks < 4; ++ks) {
            long af[4], bg[4];
            int cb = ks * 32 + g * 8;
            int sw = (rl & 7) << 4;
#pragma unroll
            for (int f = 0; f < 4; ++f) {
                int r = f * 16 + rl;
                af[f] = *(const long*)(Ab + r * 128 + (cb ^ sw));
                bg[f] = *(const long*)(Bb + r * 128 + (cb ^ sw));
            }
#pragma unroll
            for (int fi = 0; fi < 4; ++fi)
#pragma unroll
                for (int fj = 0; fj < 4; ++fj)
                    acc[fi][fj] = __builtin_amdgcn_mfma_f32_16x16x32_fp8_fp8(
                        af[fi], bg[fj], acc[fi][fj], 0, 0, 0);
        }
    }

    // epilogue: strict-causal mask, row-max over this tile's 64 cols,
    // write partial to part[b][sj][t]
    int t0g = ti * 64;
    int s0g = sj * 64;
#pragma unroll
    for (int fi = 0; fi < 4; ++fi) {
#pragma unroll
        for (int r = 0; r < 4; ++r) {
            int trow = t0g + fi * 16 + g * 4 + r;
            float m = -2.0f;
#pragma unroll
            for (int fj = 0; fj < 4; ++fj) {
                int scol = s0g + fj * 16 + rl;
                m = fmaxf(m, (scol < trow) ? acc[fi][fj][r] : -2.0f);
            }
#pragma unroll
            for (int msk = 1; msk < 16; msk <<= 1) m = fmaxf(m, __shfl_xor(m, msk));
            if (rl == 0)
                part[(((size_t)b * 32 + sj) << 11) + trow] = m;
        }
    }
}

// ------- kernel C: reduce partials + gate + recompute gelu(x), wave-per-row --
__global__ __launch_bounds__(256) void k_gate(
        const float* __restrict__ x, float* __restrict__ out,
        const float* __restrict__ ema_sim, const float* __restrict__ part,
        const float* __restrict__ log_tau,
        const float* __restrict__ log_blend,
        const float* __restrict__ logit_blend_seq) {
    int row = blockIdx.x * 4 + (threadIdx.x >> 6);
    int lane = threadIdx.x & 63;
    int b = row >> 11;
    int t = row & (TT - 1);

    int n = (t >> 6) + 1;                    // 1..32 column-chunks present
    float m = (lane < n) ? part[(((size_t)b * 32 + lane) << 11) + t] : -2.0f;
#pragma unroll
    for (int msk = 1; msk < 64; msk <<= 1) m = fmaxf(m, __shfl_xor(m, msk));

    float tau = __expf(log_tau[0]);
    float alpha = 1.f / (1.f + __expf(-log_blend[0]));
    float wseq = 1.f / (1.f + __expf(-logit_blend_seq[0]));
    float es = ema_sim[row];
    float sq = (t > 0) ? m : es;
    float fam = wseq * sq + (1.f - wseq) * es;
    float gate = 1.f - alpha + alpha * __expf(-tau * fam);

    const float4* xr = reinterpret_cast<const float4*>(x + (size_t)row * DD);
    float4* orow = reinterpret_cast<float4*>(out + (size_t)row * DD);
#pragma unroll
    for (int j = 0; j < 4; ++j) {
        float4 v = xr[j * 64 + lane];
        float4 o;
        o.x = fast_gelu(v.x) * gate;
        o.y = fast_gelu(v.y) * gate;
        o.z = fast_gelu(v.z) * gate;
        o.w = fast_gelu(v.w) * gate;
        orow[j * 64 + lane] = o;
    }
}

extern "C" void kernel_launch(void* const* d_in, const int* in_sizes, int n_in,
                              void* d_out, int out_size, void* d_ws, size_t ws_size,
                              hipStream_t stream) {
    const float* x = (const float*)d_in[0];
    const float* ema = (const float*)d_in[1];
    // d_in[2] = logit_decay (unused by reference)
    const float* log_tau = (const float*)d_in[3];
    const float* log_blend = (const float*)d_in[4];
    const float* logit_bs = (const float*)d_in[5];
    float* out = (float*)d_out;

    char* ws = (char*)d_ws;
    float* ema_sim = (float*)(ws + (4 << 10));            // 64 KB
    float* part = (float*)(ws + (132 << 10));             // 2 MB (8*32*2048 f32)
    unsigned char* onrm8 = (unsigned char*)(ws + ((size_t)2304 << 10));  // 16 MB fp8

    k_gelu_norm<<<NB * TT / 4, 256, 0, stream>>>(x, ema, (unsigned int*)onrm8, ema_sim);
    k_seqmax<<<NB * NP64, 64, 0, stream>>>(onrm8, part);
    k_gate<<<NB * TT / 4, 256, 0, stream>>>(x, out, ema_sim, part,
                                            log_tau, log_blend, logit_bs);
}